// Round 1
// baseline (132.584 us; speedup 1.0000x reference)
//
#include <hip/hip_runtime.h>
#include <hip/hip_bf16.h>

// Problem constants
#define B_ROWS 4096
#define D_DIM  256
#define N_ROWS 8192
#define NT     64          // column tiles = 8192/128

typedef __attribute__((ext_vector_type(8))) __bf16 bf16x8;
typedef __attribute__((ext_vector_type(4))) float  f32x4;

#if defined(__has_builtin)
#if __has_builtin(__builtin_amdgcn_exp2f)
#define EXP2(x) __builtin_amdgcn_exp2f(x)
#else
#define EXP2(x) exp2f(x)
#endif
#else
#define EXP2(x) exp2f(x)
#endif

static __device__ __forceinline__ float wave_reduce_add(float v) {
#pragma unroll
    for (int m = 32; m >= 1; m >>= 1) v += __shfl_xor(v, m, 64);
    return v;
}

static __device__ __forceinline__ unsigned short f2bf(float f) {
    __hip_bfloat16 h = __float2bfloat16(f);
    return __builtin_bit_cast(unsigned short, h);
}

// Kernel A: normalize rows of z1,z2 -> bf16 zb[8192][256]; pos[i] = 2*dot(z1n[i],z2n[i])
__global__ __launch_bounds__(64) void norm_pos_kernel(
    const float* __restrict__ z1, const float* __restrict__ z2,
    unsigned short* __restrict__ zb, float* __restrict__ pos)
{
    const int i = blockIdx.x;      // row 0..4095
    const int l = threadIdx.x;     // lane 0..63, 4 floats each
    const float4 a = *reinterpret_cast<const float4*>(z1 + (size_t)i * D_DIM + l * 4);
    const float4 b = *reinterpret_cast<const float4*>(z2 + (size_t)i * D_DIM + l * 4);

    float ss1 = a.x * a.x + a.y * a.y + a.z * a.z + a.w * a.w;
    float ss2 = b.x * b.x + b.y * b.y + b.z * b.z + b.w * b.w;
    float dp  = a.x * b.x + a.y * b.y + a.z * b.z + a.w * b.w;
    ss1 = wave_reduce_add(ss1);
    ss2 = wave_reduce_add(ss2);
    dp  = wave_reduce_add(dp);

    const float inv1 = rsqrtf(ss1);
    const float inv2 = rsqrtf(ss2);
    if (l == 0) pos[i] = 2.0f * dp * inv1 * inv2;

    ushort4 ua, ub;
    ua.x = f2bf(a.x * inv1); ua.y = f2bf(a.y * inv1);
    ua.z = f2bf(a.z * inv1); ua.w = f2bf(a.w * inv1);
    ub.x = f2bf(b.x * inv2); ub.y = f2bf(b.y * inv2);
    ub.z = f2bf(b.z * inv2); ub.w = f2bf(b.w * inv2);

    reinterpret_cast<ushort4*>(zb + (size_t)i * D_DIM)[l] = ua;
    reinterpret_cast<ushort4*>(zb + (size_t)(i + B_ROWS) * D_DIM)[l] = ub;
}

// Kernel B: per 128x128 tile of sim = 2*Z Z^T, accumulate exp-sums per row
// (diagonal masked), write partials[colTile][globalRow].
__global__ __launch_bounds__(256) void simsum_kernel(
    const unsigned short* __restrict__ zb, float* __restrict__ partials)
{
    const int bx = blockIdx.x;          // column tile
    const int by = blockIdx.y;          // row tile
    const int brow = by * 128, bcol = bx * 128;
    const int tid = threadIdx.x;
    const int w = tid >> 6, l = tid & 63;
    const int wr = w >> 1, wc = w & 1;  // 2x2 wave grid, each wave 64x64
    const int g = l >> 4, c15 = l & 15;

    __shared__ __align__(16) unsigned short Atile[128 * 32];
    __shared__ __align__(16) unsigned short Btile[128 * 32];
    __shared__ float rowbuf[2][128];

    f32x4 acc[4][4];
#pragma unroll
    for (int mi = 0; mi < 4; ++mi)
#pragma unroll
        for (int ni = 0; ni < 4; ++ni) acc[mi][ni] = (f32x4){0.f, 0.f, 0.f, 0.f};

#pragma unroll
    for (int ks = 0; ks < 8; ++ks) {
        const int k0 = ks * 32;
        // Stage A and B tiles: 128x32 bf16 = 8 KB each = 512 x 16B chunks, 2 per thread.
#pragma unroll
        for (int it = 0; it < 2; ++it) {
            const int c = it * 256 + tid;           // chunk index 0..511
            const int row = c >> 2;                 // 4 chunks per row of 32 bf16
            const int kc = (c & 3) * 8;
            const unsigned short* srcA = zb + (size_t)(brow + row) * D_DIM + k0 + kc;
            const unsigned short* srcB = zb + (size_t)(bcol + row) * D_DIM + k0 + kc;
            __builtin_amdgcn_global_load_lds(
                (const __attribute__((address_space(1))) void*)srcA,
                (__attribute__((address_space(3))) void*)(Atile + c * 8), 16, 0, 0);
            __builtin_amdgcn_global_load_lds(
                (const __attribute__((address_space(1))) void*)srcB,
                (__attribute__((address_space(3))) void*)(Btile + c * 8), 16, 0, 0);
        }
        __syncthreads();

        bf16x8 a[4], b[4];
#pragma unroll
        for (int mi = 0; mi < 4; ++mi)
            a[mi] = *reinterpret_cast<const bf16x8*>(
                Atile + ((wr * 64 + mi * 16 + c15) * 32 + g * 8));
#pragma unroll
        for (int ni = 0; ni < 4; ++ni)
            b[ni] = *reinterpret_cast<const bf16x8*>(
                Btile + ((wc * 64 + ni * 16 + c15) * 32 + g * 8));
#pragma unroll
        for (int mi = 0; mi < 4; ++mi)
#pragma unroll
            for (int ni = 0; ni < 4; ++ni)
                acc[mi][ni] = __builtin_amdgcn_mfma_f32_16x16x32_bf16(
                    a[mi], b[ni], acc[mi][ni], 0, 0, 0);
        __syncthreads();
    }

    // Epilogue: e = exp(2*acc) (0 on diagonal), reduce across the 128 columns.
    // C layout (m89-verified): col = lane&15, row = (lane>>4)*4 + reg.
#pragma unroll
    for (int mi = 0; mi < 4; ++mi) {
        f32x4 rs = {0.f, 0.f, 0.f, 0.f};
#pragma unroll
        for (int ni = 0; ni < 4; ++ni) {
            const int gcol = bcol + wc * 64 + ni * 16 + c15;
#pragma unroll
            for (int r = 0; r < 4; ++r) {
                const int grow = brow + wr * 64 + mi * 16 + g * 4 + r;
                // exp(2*v) = 2^(v * 2*log2(e))
                const float e = EXP2(acc[mi][ni][r] * 2.8853900817779268f);
                rs[r] += (grow == gcol) ? 0.0f : e;
            }
        }
        // reduce across 16 lanes within each lane-group (the 16 columns)
#pragma unroll
        for (int m = 1; m < 16; m <<= 1) {
#pragma unroll
            for (int r = 0; r < 4; ++r) rs[r] += __shfl_xor(rs[r], m, 64);
        }
        if (c15 == 0) {
#pragma unroll
            for (int r = 0; r < 4; ++r)
                rowbuf[wc][wr * 64 + mi * 16 + g * 4 + r] = rs[r];
        }
    }
    __syncthreads();
    if (tid < 128) {
        partials[(size_t)bx * N_ROWS + brow + tid] = rowbuf[0][tid] + rowbuf[1][tid];
    }
}

// Kernel C: lse per row, loss = mean(lse - pos)
__global__ __launch_bounds__(256) void reduce_kernel(
    const float* __restrict__ partials, const float* __restrict__ pos,
    float* __restrict__ out)
{
    const int r = blockIdx.x * 256 + threadIdx.x;
    float s = 0.f;
#pragma unroll
    for (int c = 0; c < NT; ++c) s += partials[(size_t)c * N_ROWS + r];
    float val = logf(s) - pos[r & (B_ROWS - 1)];

    val = wave_reduce_add(val);
    __shared__ float red[4];
    if ((threadIdx.x & 63) == 0) red[threadIdx.x >> 6] = val;
    __syncthreads();
    if (threadIdx.x == 0)
        atomicAdd(out, (red[0] + red[1] + red[2] + red[3]) * (1.0f / 8192.0f));
}

extern "C" void kernel_launch(void* const* d_in, const int* in_sizes, int n_in,
                              void* d_out, int out_size, void* d_ws, size_t ws_size,
                              hipStream_t stream)
{
    const float* z1 = (const float*)d_in[0];
    const float* z2 = (const float*)d_in[1];
    float* out = (float*)d_out;

    char* ws = (char*)d_ws;
    unsigned short* zb = (unsigned short*)ws;                       // 8192*256*2 = 4 MB
    float* pos         = (float*)(ws + 4u * 1024 * 1024);           // 16 KB
    float* partials    = (float*)(ws + 4u * 1024 * 1024 + 64 * 1024); // 64*8192*4 = 2 MB

    hipMemsetAsync(d_out, 0, sizeof(float), stream);
    hipLaunchKernelGGL(norm_pos_kernel, dim3(B_ROWS), dim3(64), 0, stream,
                       z1, z2, zb, pos);
    hipLaunchKernelGGL(simsum_kernel, dim3(NT, NT), dim3(256), 0, stream,
                       zb, partials);
    hipLaunchKernelGGL(reduce_kernel, dim3(N_ROWS / 256), dim3(256), 0, stream,
                       partials, pos, out);
}

// Round 4
// 90.433 us; speedup vs baseline: 1.4661x; 1.4661x over previous
//
#include <hip/hip_runtime.h>
#include <hip/hip_bf16.h>

// Problem constants
#define B_ROWS 4096
#define D_DIM  256
#define N_ROWS 8192
#define NT     64                 // 128-wide tiles per dim: 8192/128
#define NTRI   (NT * (NT + 1) / 2) // 2080 upper-triangle tiles

typedef __attribute__((ext_vector_type(8))) __bf16 bf16x8;
typedef __attribute__((ext_vector_type(4))) float  f32x4;

#if defined(__has_builtin)
#if __has_builtin(__builtin_amdgcn_exp2f)
#define EXP2(x) __builtin_amdgcn_exp2f(x)
#else
#define EXP2(x) exp2f(x)
#endif
#else
#define EXP2(x) exp2f(x)
#endif

static __device__ __forceinline__ float wave_reduce_add(float v) {
#pragma unroll
    for (int m = 32; m >= 1; m >>= 1) v += __shfl_xor(v, m, 64);
    return v;
}

static __device__ __forceinline__ unsigned short f2bf(float f) {
    __hip_bfloat16 h = __float2bfloat16(f);
    return __builtin_bit_cast(unsigned short, h);
}

// Kernel A: normalize rows of z1,z2 -> bf16 zb[8192][256];
// pos[i] = 2*dot(z1n[i],z2n[i]); also zero rowsum[] and out (saves a memset launch).
__global__ __launch_bounds__(256) void norm_pos_kernel(
    const float* __restrict__ z1, const float* __restrict__ z2,
    unsigned short* __restrict__ zb, float* __restrict__ pos,
    float* __restrict__ rowsum, float* __restrict__ out)
{
    const int w = threadIdx.x >> 6, l = threadIdx.x & 63;
    const int i = blockIdx.x * 4 + w;   // row 0..4095, one wave per row

    const float4 a = *reinterpret_cast<const float4*>(z1 + (size_t)i * D_DIM + l * 4);
    const float4 b = *reinterpret_cast<const float4*>(z2 + (size_t)i * D_DIM + l * 4);

    float ss1 = a.x * a.x + a.y * a.y + a.z * a.z + a.w * a.w;
    float ss2 = b.x * b.x + b.y * b.y + b.z * b.z + b.w * b.w;
    float dp  = a.x * b.x + a.y * b.y + a.z * b.z + a.w * b.w;
    ss1 = wave_reduce_add(ss1);
    ss2 = wave_reduce_add(ss2);
    dp  = wave_reduce_add(dp);

    const float inv1 = rsqrtf(ss1);
    const float inv2 = rsqrtf(ss2);
    if (l == 0) pos[i] = 2.0f * dp * inv1 * inv2;

    ushort4 ua, ub;
    ua.x = f2bf(a.x * inv1); ua.y = f2bf(a.y * inv1);
    ua.z = f2bf(a.z * inv1); ua.w = f2bf(a.w * inv1);
    ub.x = f2bf(b.x * inv2); ub.y = f2bf(b.y * inv2);
    ub.z = f2bf(b.z * inv2); ub.w = f2bf(b.w * inv2);

    reinterpret_cast<ushort4*>(zb + (size_t)i * D_DIM)[l] = ua;
    reinterpret_cast<ushort4*>(zb + (size_t)(i + B_ROWS) * D_DIM)[l] = ub;

    // zero accumulators for the next kernels (stream order makes this safe)
    if (threadIdx.x < 8) rowsum[blockIdx.x * 8 + threadIdx.x] = 0.0f;
    if (blockIdx.x == 0 && threadIdx.x == 0) *out = 0.0f;
}

// Kernel B: upper-triangle 128x128 tiles of sim = 2*Z Z^T.
// Off-diagonal tiles contribute exp-sums to BOTH row-lse (row-sums) and
// col-lse (col-sums, by symmetry). Diagonal tiles: row-sums only, diag masked.
// BK=64 k-steps; LDS chunk-XOR swizzle (both-sides: pre-swizzled global src
// for global_load_lds + swizzled ds_read) kills the 8-way bank conflict.
__global__ __launch_bounds__(256) void simsum_kernel(
    const unsigned short* __restrict__ zb, float* __restrict__ rowsum)
{
    // decode upper-triangle tile index -> (by, bx), bx >= by
    const int idx = blockIdx.x;
    int by = (int)((2.0f * NT + 1.0f -
                    sqrtf((2.0f * NT + 1.0f) * (2.0f * NT + 1.0f) - 8.0f * idx)) * 0.5f);
    if (by < 0) by = 0;
    if (by > NT - 1) by = NT - 1;
#define TRI_START(b) ((b) * NT - (((b) * ((b) - 1)) >> 1))
    while (TRI_START(by) > idx) --by;
    while (by < NT - 1 && TRI_START(by + 1) <= idx) ++by;
    const int bx = by + (idx - TRI_START(by));
#undef TRI_START

    const int brow = by * 128, bcol = bx * 128;
    const bool isdiag = (bx == by);
    const int tid = threadIdx.x;
    const int w = tid >> 6, l = tid & 63;
    const int wr = w >> 1, wc = w & 1;   // 2x2 wave grid, each wave owns 64x64
    const int g = l >> 4, c15 = l & 15;

    __shared__ __align__(16) unsigned short Atile[128 * 64];
    __shared__ __align__(16) unsigned short Btile[128 * 64];
    __shared__ float rowbuf[2][128];
    __shared__ float colbuf[2][128];

    f32x4 acc[4][4];
#pragma unroll
    for (int mi = 0; mi < 4; ++mi)
#pragma unroll
        for (int ni = 0; ni < 4; ++ni) acc[mi][ni] = (f32x4){0.f, 0.f, 0.f, 0.f};

#pragma unroll
    for (int ks = 0; ks < 4; ++ks) {
        const int k0 = ks * 64;
        // Stage A,B tiles: 128 rows x 8 chunks(16B) = 1024 chunks each, 4/thread.
        // LDS dest is linear (global_load_lds requirement); the global SOURCE is
        // pre-swizzled so that LDS[row][cpos] holds global chunk cpos^(row&7).
#pragma unroll
        for (int it = 0; it < 4; ++it) {
            const int c = it * 256 + tid;           // 0..1023
            const int row = c >> 3;
            const int cpos = c & 7;
            const int kc = (cpos ^ (row & 7)) * 8;  // swizzled global chunk
            const unsigned short* srcA = zb + (size_t)(brow + row) * D_DIM + k0 + kc;
            const unsigned short* srcB = zb + (size_t)(bcol + row) * D_DIM + k0 + kc;
            __builtin_amdgcn_global_load_lds(
                (const __attribute__((address_space(1))) void*)srcA,
                (__attribute__((address_space(3))) void*)(Atile + c * 8), 16, 0, 0);
            __builtin_amdgcn_global_load_lds(
                (const __attribute__((address_space(1))) void*)srcB,
                (__attribute__((address_space(3))) void*)(Btile + c * 8), 16, 0, 0);
        }
        __syncthreads();

#pragma unroll
        for (int s = 0; s < 2; ++s) {               // two K=32 sub-steps
            bf16x8 a[4], b[4];
#pragma unroll
            for (int mi = 0; mi < 4; ++mi) {
                const int row = wr * 64 + mi * 16 + c15;
                a[mi] = *reinterpret_cast<const bf16x8*>(
                    Atile + row * 64 + (((s * 4 + g) ^ (row & 7)) * 8));
            }
#pragma unroll
            for (int ni = 0; ni < 4; ++ni) {
                const int row = wc * 64 + ni * 16 + c15;
                b[ni] = *reinterpret_cast<const bf16x8*>(
                    Btile + row * 64 + (((s * 4 + g) ^ (row & 7)) * 8));
            }
#pragma unroll
            for (int mi = 0; mi < 4; ++mi)
#pragma unroll
                for (int ni = 0; ni < 4; ++ni)
                    acc[mi][ni] = __builtin_amdgcn_mfma_f32_16x16x32_bf16(
                        a[mi], b[ni], acc[mi][ni], 0, 0, 0);
        }
        __syncthreads();
    }

    // Epilogue. C layout (m89): col = lane&15, row = (lane>>4)*4 + reg.
    float colacc[4] = {0.f, 0.f, 0.f, 0.f};
#pragma unroll
    for (int mi = 0; mi < 4; ++mi) {
        f32x4 rs = {0.f, 0.f, 0.f, 0.f};
#pragma unroll
        for (int ni = 0; ni < 4; ++ni) {
            const int gcol = bcol + wc * 64 + ni * 16 + c15;
#pragma unroll
            for (int r = 0; r < 4; ++r) {
                const int grow = brow + wr * 64 + mi * 16 + g * 4 + r;
                // exp(2*v) = 2^(v * 2*log2(e))
                float e = EXP2(acc[mi][ni][r] * 2.8853900817779268f);
                if (isdiag && grow == gcol) e = 0.f;
                rs[r] += e;
                colacc[ni] += e;
            }
        }
#pragma unroll
        for (int m = 1; m < 16; m <<= 1)
#pragma unroll
            for (int r = 0; r < 4; ++r) rs[r] += __shfl_xor(rs[r], m, 64);
        if (c15 == 0)
#pragma unroll
            for (int r = 0; r < 4; ++r)
                rowbuf[wc][wr * 64 + mi * 16 + g * 4 + r] = rs[r];
    }
    // column sums: reduce across the 4 lane-groups (rows within the wave span)
#pragma unroll
    for (int ni = 0; ni < 4; ++ni) {
        colacc[ni] += __shfl_xor(colacc[ni], 16, 64);
        colacc[ni] += __shfl_xor(colacc[ni], 32, 64);
    }
    if (l < 16)
#pragma unroll
        for (int ni = 0; ni < 4; ++ni)
            colbuf[wr][wc * 64 + ni * 16 + c15] = colacc[ni];
    __syncthreads();

    if (tid < 128) {
        atomicAdd(&rowsum[brow + tid], rowbuf[0][tid] + rowbuf[1][tid]);
        if (!isdiag)
            atomicAdd(&rowsum[bcol + tid], colbuf[0][tid] + colbuf[1][tid]);
    }
}

// Kernel C: lse per row, loss = mean(lse - pos)
__global__ __launch_bounds__(256) void reduce_kernel(
    const float* __restrict__ rowsum, const float* __restrict__ pos,
    float* __restrict__ out)
{
    const int r = blockIdx.x * 256 + threadIdx.x;
    float val = logf(rowsum[r]) - pos[r & (B_ROWS - 1)];

    val = wave_reduce_add(val);
    __shared__ float red[4];
    if ((threadIdx.x & 63) == 0) red[threadIdx.x >> 6] = val;
    __syncthreads();
    if (threadIdx.x == 0)
        atomicAdd(out, (red[0] + red[1] + red[2] + red[3]) * (1.0f / 8192.0f));
}

extern "C" void kernel_launch(void* const* d_in, const int* in_sizes, int n_in,
                              void* d_out, int out_size, void* d_ws, size_t ws_size,
                              hipStream_t stream)
{
    const float* z1 = (const float*)d_in[0];
    const float* z2 = (const float*)d_in[1];
    float* out = (float*)d_out;

    char* ws = (char*)d_ws;
    unsigned short* zb = (unsigned short*)ws;                 // 8192*256*2 = 4 MB
    float* pos         = (float*)(ws + 4u * 1024 * 1024);     // 16 KB
    float* rowsum      = (float*)(ws + 4u * 1024 * 1024 + 64 * 1024); // 32 KB

    hipLaunchKernelGGL(norm_pos_kernel, dim3(B_ROWS / 4), dim3(256), 0, stream,
                       z1, z2, zb, pos, rowsum, out);
    hipLaunchKernelGGL(simsum_kernel, dim3(NTRI), dim3(256), 0, stream,
                       zb, rowsum);
    hipLaunchKernelGGL(reduce_kernel, dim3(N_ROWS / 256), dim3(256), 0, stream,
                       rowsum, pos, out);
}